// Round 1
// baseline (4895.472 us; speedup 1.0000x reference)
//
#include <hip/hip_runtime.h>

// LSTM encoder, persistent-kernel formulation.
// B=128, T=512, I=256, H=512.
// 8 clusters (one per XCD under round-robin blockIdx%8 mapping) x 32 WGs.
// Cluster c owns batch rows [16c,16c+16); WG w owns h-cols [16w,16w+16).
// Waves 0..3 of a WG compute gates z,s,f,o via mfma_f32_16x16x32_bf16 with
// R (K=512) and W (K=256) B-fragments resident in registers for all 512 steps.
// h exchanged per step via double-buffered global bf16 buffer + per-cluster
// agent-scope release/acquire barrier (handles cross-XCD L2 non-coherence).

#define B_ 128
#define T_ 512
#define I_ 256
#define H_ 512

typedef __attribute__((ext_vector_type(8))) short bf16x8;
typedef __attribute__((ext_vector_type(4))) float f32x4;

__device__ __forceinline__ unsigned short f2bf(float f) {
  union { float f; unsigned u; } v; v.f = f;
  unsigned r = v.u + 0x7FFFu + ((v.u >> 16) & 1u);  // RNE; inputs finite
  return (unsigned short)(r >> 16);
}

__device__ __forceinline__ float sigm_f(float x) { return 1.f / (1.f + __expf(-x)); }
// tanh via exp2-backed expf; forms chosen to avoid inf/inf at saturation.
__device__ __forceinline__ float tanh_f(float x) { return 1.f - 2.f / (__expf(2.f * x) + 1.f); }

__global__ __launch_bounds__(256, 1)
void lstm_persistent(const float* __restrict__ x,
                     const float* __restrict__ Wz, const float* __restrict__ Ws,
                     const float* __restrict__ Wf, const float* __restrict__ Wo,
                     const float* __restrict__ Rz, const float* __restrict__ Rs,
                     const float* __restrict__ Rf, const float* __restrict__ Ro,
                     const float* __restrict__ bz, const float* __restrict__ bs,
                     const float* __restrict__ bf_, const float* __restrict__ bo,
                     float* __restrict__ out,
                     unsigned short* __restrict__ hbuf,   // [2][128][512] bf16
                     unsigned* __restrict__ cnt) {        // [8] stride 32 u32
  const int tid = threadIdx.x;
  const int bid = blockIdx.x;
  const int cluster = bid & 7;     // XCD-affine cluster id
  const int w = bid >> 3;          // 0..31: column-slice owner within cluster
  const int rowbase = cluster * 16;  // batch rows
  const int jbase = w * 16;          // h columns
  const int g = tid >> 6;            // wave id == gate (0=z,1=s,2=f,3=o)
  const int lane = tid & 63;
  const int n16 = lane & 15;         // fragment row/col index
  const int kg = lane >> 4;          // k-group within fragment

  __shared__ __align__(16) char h_lds[16 * 1024];  // [16 rows][512 bf16], XOR-swizzled
  __shared__ __align__(16) char x_lds[16 * 512];   // [16 rows][256 bf16], XOR-swizzled
  __shared__ float gates[4][16][16];               // per-gate activated tiles

  const float* Wg = (g == 0) ? Wz : (g == 1) ? Ws : (g == 2) ? Wf : Wo;
  const float* Rg = (g == 0) ? Rz : (g == 1) ? Rs : (g == 2) ? Rf : Ro;
  const float* bg = (g == 0) ? bz : (g == 1) ? bs : (g == 2) ? bf_ : bo;

  // ---- Load B-fragments (R: 16 k-tiles, W: 8 k-tiles) into registers, once.
  // B-frag layout for mfma_f32_16x16x32_bf16: lane holds B[k,n] with n=lane&15,
  // k = 32*kt + 8*(lane>>4) + {0..7} (8 consecutive K elems of row j of R/W).
  bf16x8 rB[16];
  bf16x8 wB[8];
  {
    const float* rrow = Rg + (size_t)(jbase + n16) * H_;
#pragma unroll
    for (int kt = 0; kt < 16; ++kt) {
      int k0 = kt * 32 + kg * 8;
      float4 f0 = *(const float4*)(rrow + k0);
      float4 f1 = *(const float4*)(rrow + k0 + 4);
      bf16x8 t;
      t[0] = (short)f2bf(f0.x); t[1] = (short)f2bf(f0.y);
      t[2] = (short)f2bf(f0.z); t[3] = (short)f2bf(f0.w);
      t[4] = (short)f2bf(f1.x); t[5] = (short)f2bf(f1.y);
      t[6] = (short)f2bf(f1.z); t[7] = (short)f2bf(f1.w);
      rB[kt] = t;
    }
    const float* wrow = Wg + (size_t)(jbase + n16) * I_;
#pragma unroll
    for (int kt = 0; kt < 8; ++kt) {
      int k0 = kt * 32 + kg * 8;
      float4 f0 = *(const float4*)(wrow + k0);
      float4 f1 = *(const float4*)(wrow + k0 + 4);
      bf16x8 t;
      t[0] = (short)f2bf(f0.x); t[1] = (short)f2bf(f0.y);
      t[2] = (short)f2bf(f0.z); t[3] = (short)f2bf(f0.w);
      t[4] = (short)f2bf(f1.x); t[5] = (short)f2bf(f1.y);
      t[6] = (short)f2bf(f1.z); t[7] = (short)f2bf(f1.w);
      wB[kt] = t;
    }
  }
  const float bias = bg[jbase + n16];

  const int cb = tid >> 4;  // combine: batch row 0..15
  const int cn = tid & 15;  // combine: col within slice

  float c_state = 0.f;
  float h_sum = 0.f;
  unsigned* mycnt = cnt + cluster * 32;

  // ---- stage x[rowbase.., t=0] -> x_lds (bf16, swizzled)
  {
#pragma unroll
    for (int i = 0; i < 4; ++i) {
      int ci = i * 256 + tid;
      int row = ci >> 6;
      int cf = (ci & 63) * 4;
      const float4 v = *(const float4*)(x + ((size_t)(rowbase + row) * T_ + 0) * I_ + cf);
      ushort4 pk;
      pk.x = f2bf(v.x); pk.y = f2bf(v.y); pk.z = f2bf(v.z); pk.w = f2bf(v.w);
      *(ushort4*)(&x_lds[(row * 512 + cf * 2) ^ ((row & 7) << 4)]) = pk;
    }
  }

  for (int t = 0; t < T_; ++t) {
    const unsigned short* hin = hbuf + (size_t)(t & 1) * (B_ * H_);
    unsigned short* hout = hbuf + (size_t)((t + 1) & 1) * (B_ * H_);

    // ---- stage h(t-1) [16 rows x 512] bf16 -> h_lds (swizzled)
#pragma unroll
    for (int i = 0; i < 4; ++i) {
      int ci = i * 256 + tid;
      int row = ci >> 6;          // 64 x 16B chunks per row
      int ib = (ci & 63) * 16;
      uint4 v = *(const uint4*)((const char*)hin + (size_t)(rowbase + row) * 1024 + ib);
      *(uint4*)(&h_lds[(row * 1024 + ib) ^ ((row & 7) << 4)]) = v;
    }
    __syncthreads();

    // ---- MFMA: preact = b + x_t @ Wg^T + h @ Rg^T   (per wave: one gate)
    f32x4 acc = {bias, bias, bias, bias};
#pragma unroll
    for (int kt = 0; kt < 8; ++kt) {
      int k0 = kt * 32 + kg * 8;
      bf16x8 a = *(const bf16x8*)(&x_lds[(n16 * 512 + k0 * 2) ^ ((n16 & 7) << 4)]);
      acc = __builtin_amdgcn_mfma_f32_16x16x32_bf16(a, wB[kt], acc, 0, 0, 0);
    }
#pragma unroll
    for (int kt = 0; kt < 16; ++kt) {
      int k0 = kt * 32 + kg * 8;
      bf16x8 a = *(const bf16x8*)(&h_lds[(n16 * 1024 + k0 * 2) ^ ((n16 & 7) << 4)]);
      acc = __builtin_amdgcn_mfma_f32_16x16x32_bf16(a, rB[kt], acc, 0, 0, 0);
    }
    // activation; C/D layout: col = lane&15, row = (lane>>4)*4 + r  [m89]
#pragma unroll
    for (int r = 0; r < 4; ++r) {
      float p = acc[r];
      float v = (g == 0) ? tanh_f(p) : sigm_f(p);
      gates[g][kg * 4 + r][n16] = v;
    }
    __syncthreads();

    // ---- combine: one (b,j) cell per thread; c_state/h_sum in registers
    float zv = gates[0][cb][cn];
    float sv = gates[1][cb][cn];
    float fv = gates[2][cb][cn];
    float ov = gates[3][cb][cn];
    c_state = sv * zv + fv * c_state;
    float hv = ov * tanh_f(c_state);
    h_sum += hv;
    hout[(size_t)(rowbase + cb) * H_ + (jbase + cn)] = f2bf(hv);

    if (t + 1 < T_) {
      // ---- prefetch x for t+1 (HBM latency hides under the barrier spin)
#pragma unroll
      for (int i = 0; i < 4; ++i) {
        int ci = i * 256 + tid;
        int row = ci >> 6;
        int cf = (ci & 63) * 4;
        const float4 v =
            *(const float4*)(x + ((size_t)(rowbase + row) * T_ + (t + 1)) * I_ + cf);
        ushort4 pk;
        pk.x = f2bf(v.x); pk.y = f2bf(v.y); pk.z = f2bf(v.z); pk.w = f2bf(v.w);
        *(ushort4*)(&x_lds[(row * 512 + cf * 2) ^ ((row & 7) << 4)]) = pk;
      }
      // ---- per-cluster barrier. __syncthreads drains vmcnt (h stores in L2);
      // RELEASE add at agent scope writes back this XCD's L2 (cross-XCD vis),
      // ACQUIRE spin invalidates stale L1/L2 lines before next h staging.
      __syncthreads();
      if (tid == 0) {
        __hip_atomic_fetch_add(mycnt, 1u, __ATOMIC_RELEASE, __HIP_MEMORY_SCOPE_AGENT);
        unsigned tgt = 32u * (unsigned)(t + 1);
        while (__hip_atomic_load(mycnt, __ATOMIC_ACQUIRE, __HIP_MEMORY_SCOPE_AGENT) < tgt) {
          __builtin_amdgcn_s_sleep(2);
        }
      }
      __syncthreads();
    }
  }

  // ---- epilogue: mean over T
  out[(size_t)(rowbase + cb) * H_ + (jbase + cn)] = h_sum * (1.0f / (float)T_);
}

extern "C" void kernel_launch(void* const* d_in, const int* in_sizes, int n_in,
                              void* d_out, int out_size, void* d_ws, size_t ws_size,
                              hipStream_t stream) {
  const float* x  = (const float*)d_in[0];
  const float* Wz = (const float*)d_in[1];
  const float* Ws = (const float*)d_in[2];
  const float* Wf = (const float*)d_in[3];
  const float* Wo = (const float*)d_in[4];
  const float* Rz = (const float*)d_in[5];
  const float* Rs = (const float*)d_in[6];
  const float* Rf = (const float*)d_in[7];
  const float* Ro = (const float*)d_in[8];
  const float* bz = (const float*)d_in[9];
  const float* bs = (const float*)d_in[10];
  const float* bf_ = (const float*)d_in[11];
  const float* bo = (const float*)d_in[12];

  // ws layout: [0, 256KiB) h double-buffer (bf16), [256KiB, +1KiB) barrier counters
  unsigned short* hbuf = (unsigned short*)d_ws;
  unsigned* cnt = (unsigned*)((char*)d_ws + 262144);

  // zero h_buf[0] (initial hidden state) and the barrier counters each launch
  hipMemsetAsync(d_ws, 0, 262144 + 1024, stream);

  lstm_persistent<<<256, 256, 0, stream>>>(x, Wz, Ws, Wf, Wo, Rz, Rs, Rf, Ro,
                                           bz, bs, bf_, bo,
                                           (float*)d_out, hbuf, cnt);
}

// Round 5
// 2928.325 us; speedup vs baseline: 1.6718x; 1.6718x over previous
//
#include <hip/hip_runtime.h>

// LSTM encoder, persistent-kernel formulation (round 2 kernel, resubmitted —
// three consecutive GPU-acquisition timeouts; no measurement yet).
// B=128, T=512, I=256, H=512.
// 8 clusters x 32 WGs; cluster c owns batch rows [16c,16c+16); WG w owns
// h-cols [16w,16w+16). Waves 0..3 = gates z,s,f,o, R/W fragments in registers.
//
// Round-2 change: NO cache-maintenance sync. h exchanged through the Infinity
// Cache via relaxed agent-scope atomics (sc1 bypass => coherent under any
// WG->XCD mapping, no buffer_inv/buffer_wbl2). Barrier = per-WG monotonic
// flag array + wave-parallel poll (one coalesced IC line read per iteration).

#define B_ 128
#define T_ 512
#define I_ 256
#define H_ 512

typedef __attribute__((ext_vector_type(8))) short bf16x8;
typedef __attribute__((ext_vector_type(4))) float f32x4;

__device__ __forceinline__ unsigned short f2bf(float f) {
  union { float f; unsigned u; } v; v.f = f;
  unsigned r = v.u + 0x7FFFu + ((v.u >> 16) & 1u);  // RNE; inputs finite
  return (unsigned short)(r >> 16);
}

__device__ __forceinline__ float sigm_f(float x) { return 1.f / (1.f + __expf(-x)); }
__device__ __forceinline__ float tanh_f(float x) { return 1.f - 2.f / (__expf(2.f * x) + 1.f); }

__global__ __launch_bounds__(256, 1)
void lstm_persistent(const float* __restrict__ x,
                     const float* __restrict__ Wz, const float* __restrict__ Ws,
                     const float* __restrict__ Wf, const float* __restrict__ Wo,
                     const float* __restrict__ Rz, const float* __restrict__ Rs,
                     const float* __restrict__ Rf, const float* __restrict__ Ro,
                     const float* __restrict__ bz, const float* __restrict__ bs,
                     const float* __restrict__ bf_, const float* __restrict__ bo,
                     float* __restrict__ out,
                     unsigned* __restrict__ hbuf32,   // [2][128][256] u32 (2xbf16)
                     unsigned* __restrict__ flags) {  // [8][64] u32, monotonic
  const int tid = threadIdx.x;
  const int bid = blockIdx.x;
  const int cluster = bid & 7;
  const int w = bid >> 3;
  const int rowbase = cluster * 16;
  const int jbase = w * 16;
  const int g = tid >> 6;            // wave id == gate (0=z,1=s,2=f,3=o)
  const int lane = tid & 63;
  const int n16 = lane & 15;
  const int kg = lane >> 4;

  __shared__ __align__(16) char h_lds[16 * 1024];  // [16 rows][512 bf16], XOR-swizzled
  __shared__ __align__(16) char x_lds[16 * 512];   // [16 rows][256 bf16], XOR-swizzled
  __shared__ float gates[4][16][16];

  const float* Wg = (g == 0) ? Wz : (g == 1) ? Ws : (g == 2) ? Wf : Wo;
  const float* Rg = (g == 0) ? Rz : (g == 1) ? Rs : (g == 2) ? Rf : Ro;
  const float* bg = (g == 0) ? bz : (g == 1) ? bs : (g == 2) ? bf_ : bo;

  // ---- R (16 k-tiles) and W (8 k-tiles) B-fragments resident in registers.
  bf16x8 rB[16];
  bf16x8 wB[8];
  {
    const float* rrow = Rg + (size_t)(jbase + n16) * H_;
#pragma unroll
    for (int kt = 0; kt < 16; ++kt) {
      int k0 = kt * 32 + kg * 8;
      float4 f0 = *(const float4*)(rrow + k0);
      float4 f1 = *(const float4*)(rrow + k0 + 4);
      bf16x8 t;
      t[0] = (short)f2bf(f0.x); t[1] = (short)f2bf(f0.y);
      t[2] = (short)f2bf(f0.z); t[3] = (short)f2bf(f0.w);
      t[4] = (short)f2bf(f1.x); t[5] = (short)f2bf(f1.y);
      t[6] = (short)f2bf(f1.z); t[7] = (short)f2bf(f1.w);
      rB[kt] = t;
    }
    const float* wrow = Wg + (size_t)(jbase + n16) * I_;
#pragma unroll
    for (int kt = 0; kt < 8; ++kt) {
      int k0 = kt * 32 + kg * 8;
      float4 f0 = *(const float4*)(wrow + k0);
      float4 f1 = *(const float4*)(wrow + k0 + 4);
      bf16x8 t;
      t[0] = (short)f2bf(f0.x); t[1] = (short)f2bf(f0.y);
      t[2] = (short)f2bf(f0.z); t[3] = (short)f2bf(f0.w);
      t[4] = (short)f2bf(f1.x); t[5] = (short)f2bf(f1.y);
      t[6] = (short)f2bf(f1.z); t[7] = (short)f2bf(f1.w);
      wB[kt] = t;
    }
  }
  const float bias = bg[jbase + n16];

  const int cb = tid >> 4;  // combine: batch row 0..15
  const int cn = tid & 15;  // combine: col within slice

  float c_state = 0.f;
  float h_sum = 0.f;
  unsigned* flg = flags + cluster * 64;  // 32 used; 256B stride isolates lines

  // ---- stage x[rowbase.., t=0] -> x_lds (bf16, swizzled)
#pragma unroll
  for (int i = 0; i < 4; ++i) {
    int ci = i * 256 + tid;
    int row = ci >> 6;
    int cf = (ci & 63) * 4;
    const float4 v = *(const float4*)(x + ((size_t)(rowbase + row) * T_ + 0) * I_ + cf);
    ushort4 pk;
    pk.x = f2bf(v.x); pk.y = f2bf(v.y); pk.z = f2bf(v.z); pk.w = f2bf(v.w);
    *(ushort4*)(&x_lds[(row * 512 + cf * 2) ^ ((row & 7) << 4)]) = pk;
  }

  for (int t = 0; t < T_; ++t) {
    unsigned* hin32 = hbuf32 + (size_t)(t & 1) * (B_ * H_ / 2);
    unsigned* hout32 = hbuf32 + (size_t)((t + 1) & 1) * (B_ * H_ / 2);

    // ---- stage h(t-1): 16 rows x 256 dwords from IC (sc1 loads) -> LDS
    // thread tid covers dword column tid of every row k.
#pragma unroll
    for (int k = 0; k < 16; ++k) {
      unsigned v = __hip_atomic_load(&hin32[(size_t)(rowbase + k) * 256 + tid],
                                     __ATOMIC_RELAXED, __HIP_MEMORY_SCOPE_AGENT);
      *(unsigned*)(&h_lds[(k * 1024 + tid * 4) ^ ((k & 7) << 4)]) = v;
    }
    __syncthreads();

    // ---- MFMA: preact = b + x_t @ Wg^T + h @ Rg^T   (per wave: one gate)
    f32x4 acc = {bias, bias, bias, bias};
#pragma unroll
    for (int kt = 0; kt < 8; ++kt) {
      int k0 = kt * 32 + kg * 8;
      bf16x8 a = *(const bf16x8*)(&x_lds[(n16 * 512 + k0 * 2) ^ ((n16 & 7) << 4)]);
      acc = __builtin_amdgcn_mfma_f32_16x16x32_bf16(a, wB[kt], acc, 0, 0, 0);
    }
#pragma unroll
    for (int kt = 0; kt < 16; ++kt) {
      int k0 = kt * 32 + kg * 8;
      bf16x8 a = *(const bf16x8*)(&h_lds[(n16 * 1024 + k0 * 2) ^ ((n16 & 7) << 4)]);
      acc = __builtin_amdgcn_mfma_f32_16x16x32_bf16(a, rB[kt], acc, 0, 0, 0);
    }
    // C/D layout: col = lane&15, row = (lane>>4)*4 + r
#pragma unroll
    for (int r = 0; r < 4; ++r) {
      float p = acc[r];
      float v = (g == 0) ? tanh_f(p) : sigm_f(p);
      gates[g][kg * 4 + r][n16] = v;
    }
    __syncthreads();

    // ---- combine: one (b,j) cell per thread
    float zv = gates[0][cb][cn];
    float sv = gates[1][cb][cn];
    float fv = gates[2][cb][cn];
    float ov = gates[3][cb][cn];
    c_state = sv * zv + fv * c_state;
    float hv = ov * tanh_f(c_state);
    h_sum += hv;

    // ---- publish h: pack 2 cols/dword, relaxed agent store (straight to IC)
    {
      unsigned hb = (unsigned)f2bf(hv);
      unsigned nb = __shfl_down(hb, 1, 64);  // lane+1 = col cn+1, same row
      if ((lane & 1) == 0) {
        unsigned packed = hb | (nb << 16);
        __hip_atomic_store(&hout32[((size_t)(rowbase + cb) << 8) + ((jbase + cn) >> 1)],
                           packed, __ATOMIC_RELAXED, __HIP_MEMORY_SCOPE_AGENT);
      }
    }

    if (t + 1 < T_) {
      // __syncthreads drains vmcnt(0) for every thread => all h stores are at
      // the coherence point before the flag below is published.
      __syncthreads();
      if (tid == 0) {
        __hip_atomic_store(&flg[w], (unsigned)(t + 1),
                           __ATOMIC_RELAXED, __HIP_MEMORY_SCOPE_AGENT);
      }
      // ---- x prefetch for t+1 overlaps the barrier wait
#pragma unroll
      for (int i = 0; i < 4; ++i) {
        int ci = i * 256 + tid;
        int row = ci >> 6;
        int cf = (ci & 63) * 4;
        const float4 v =
            *(const float4*)(x + ((size_t)(rowbase + row) * T_ + (t + 1)) * I_ + cf);
        ushort4 pk;
        pk.x = f2bf(v.x); pk.y = f2bf(v.y); pk.z = f2bf(v.z); pk.w = f2bf(v.w);
        *(ushort4*)(&x_lds[(row * 512 + cf * 2) ^ ((row & 7) << 4)]) = pk;
      }
      // ---- wave-parallel poll: lane i watches WG i's flag (one IC line)
      if (tid < 64) {
        const unsigned tgt = (unsigned)(t + 1);
        for (;;) {
          unsigned v = __hip_atomic_load(&flg[lane & 31],
                                         __ATOMIC_RELAXED, __HIP_MEMORY_SCOPE_AGENT);
          if (__all((int)(v >= tgt))) break;
        }
      }
      __syncthreads();
    }
  }

  // ---- epilogue: mean over T
  out[(size_t)(rowbase + cb) * H_ + (jbase + cn)] = h_sum * (1.0f / (float)T_);
}

extern "C" void kernel_launch(void* const* d_in, const int* in_sizes, int n_in,
                              void* d_out, int out_size, void* d_ws, size_t ws_size,
                              hipStream_t stream) {
  const float* x  = (const float*)d_in[0];
  const float* Wz = (const float*)d_in[1];
  const float* Ws = (const float*)d_in[2];
  const float* Wf = (const float*)d_in[3];
  const float* Wo = (const float*)d_in[4];
  const float* Rz = (const float*)d_in[5];
  const float* Rs = (const float*)d_in[6];
  const float* Rf = (const float*)d_in[7];
  const float* Ro = (const float*)d_in[8];
  const float* bz = (const float*)d_in[9];
  const float* bs = (const float*)d_in[10];
  const float* bf_ = (const float*)d_in[11];
  const float* bo = (const float*)d_in[12];

  // ws: [0, 256KiB) h double-buffer (2xbf16 per u32), then 8x64 u32 flags
  unsigned* hbuf32 = (unsigned*)d_ws;
  unsigned* flags = (unsigned*)((char*)d_ws + 262144);

  hipMemsetAsync(d_ws, 0, 262144 + 2048, stream);

  lstm_persistent<<<256, 256, 0, stream>>>(x, Wz, Ws, Wf, Wo, Rz, Rs, Rf, Ro,
                                           bz, bs, bf_, bo,
                                           (float*)d_out, hbuf32, flags);
}

// Round 9
// 2197.651 us; speedup vs baseline: 2.2276x; 1.3325x over previous
//
#include <hip/hip_runtime.h>

// LSTM encoder, persistent-kernel formulation (round 9).
// B=128, T=512, I=256, H=512.
// 8 clusters x 32 WGs; cluster c owns batch rows [16c,16c+16); WG w owns
// h-cols [16w,16w+16). Waves 0..3 = gates z,s,f,o; R/W fragments in registers.
//
// Protocol = round-5 (PROVEN: 2928us, absmax 0.0039): h exchange and barrier
// flags via relaxed agent-scope atomics through the Infinity Cache; no cache
// maintenance ops; ordering via __syncthreads vmcnt drain. FAST/L2 path from
// rounds 6-8 is REMOVED (round-8 guard proved its visibility model wrong).
//
// Round-9 deltas (all correctness-neutral vs round 5):
//  1. Throttled poll: wave 0 only, immediate first check then s_sleep(8)
//     (~0.2us) between checks -> ~25-400x less IC poll traffic (the theory:
//     spin-wait self-interference at the IC dominated round 5's step time).
//     Bounded spin (sticky dead flag) kept as anti-hang insurance.
//  2. x-projection off the critical path: accW(t+1) = bias + x(t+1)@W^T
//     computed during the barrier wait; x double-buffered in LDS; x loads
//     issued a full step early (HBM latency hidden under compute).
//  3. h staged with b64 agent loads (half the issue count of round 5).

#define B_ 128
#define T_ 512
#define I_ 256
#define H_ 512

typedef __attribute__((ext_vector_type(8))) short bf16x8;
typedef __attribute__((ext_vector_type(4))) float f32x4;

__device__ __forceinline__ unsigned short f2bf(float f) {
  union { float f; unsigned u; } v; v.f = f;
  unsigned r = v.u + 0x7FFFu + ((v.u >> 16) & 1u);  // RNE; inputs finite
  return (unsigned short)(r >> 16);
}

__device__ __forceinline__ float sigm_f(float x) { return 1.f / (1.f + __expf(-x)); }
__device__ __forceinline__ float tanh_f(float x) { return 1.f - 2.f / (__expf(2.f * x) + 1.f); }

__global__ __launch_bounds__(256, 1)
void lstm_persistent(const float* __restrict__ x,
                     const float* __restrict__ Wz, const float* __restrict__ Ws,
                     const float* __restrict__ Wf, const float* __restrict__ Wo,
                     const float* __restrict__ Rz, const float* __restrict__ Rs,
                     const float* __restrict__ Rf, const float* __restrict__ Ro,
                     const float* __restrict__ bz, const float* __restrict__ bs,
                     const float* __restrict__ bf_, const float* __restrict__ bo,
                     float* __restrict__ out,
                     unsigned* __restrict__ hbuf32,   // [2][128][256] u32 (2xbf16)
                     unsigned* __restrict__ flags) {  // [8][64] u32, monotonic
  const int tid = threadIdx.x;
  const int bid = blockIdx.x;
  const int cluster = bid & 7;
  const int w = bid >> 3;
  const int rowbase = cluster * 16;
  const int jbase = w * 16;
  const int g = tid >> 6;            // wave id == gate (0=z,1=s,2=f,3=o)
  const int lane = tid & 63;
  const int n16 = lane & 15;
  const int kg = lane >> 4;

  __shared__ __align__(16) char h_lds[16 * 1024];   // [16 rows][512 bf16], XOR-swizzled
  __shared__ __align__(16) char x_lds0[16 * 512];   // [16 rows][256 bf16], XOR-swizzled
  __shared__ __align__(16) char x_lds1[16 * 512];
  __shared__ float gates[4][16][16];

  const float* Wg = (g == 0) ? Wz : (g == 1) ? Ws : (g == 2) ? Wf : Wo;
  const float* Rg = (g == 0) ? Rz : (g == 1) ? Rs : (g == 2) ? Rf : Ro;
  const float* bg = (g == 0) ? bz : (g == 1) ? bs : (g == 2) ? bf_ : bo;

  // ---- stage x(0)->x_lds0, x(1)->x_lds1
#pragma unroll
  for (int i = 0; i < 4; ++i) {
    int ci = i * 256 + tid;
    int row = ci >> 6, cf = (ci & 63) * 4;
    const float4 v0 = *(const float4*)(x + ((size_t)(rowbase + row) * T_ + 0) * I_ + cf);
    const float4 v1 = *(const float4*)(x + ((size_t)(rowbase + row) * T_ + 1) * I_ + cf);
    ushort4 p0, p1;
    p0.x = f2bf(v0.x); p0.y = f2bf(v0.y); p0.z = f2bf(v0.z); p0.w = f2bf(v0.w);
    p1.x = f2bf(v1.x); p1.y = f2bf(v1.y); p1.z = f2bf(v1.z); p1.w = f2bf(v1.w);
    *(ushort4*)(&x_lds0[(row * 512 + cf * 2) ^ ((row & 7) << 4)]) = p0;
    *(ushort4*)(&x_lds1[(row * 512 + cf * 2) ^ ((row & 7) << 4)]) = p1;
  }

  // ---- R (16 k-tiles) and W (8 k-tiles) B-fragments resident in registers.
  bf16x8 rB[16];
  bf16x8 wB[8];
  {
    const float* rrow = Rg + (size_t)(jbase + n16) * H_;
#pragma unroll
    for (int kt = 0; kt < 16; ++kt) {
      int k0 = kt * 32 + kg * 8;
      float4 f0 = *(const float4*)(rrow + k0);
      float4 f1 = *(const float4*)(rrow + k0 + 4);
      bf16x8 t;
      t[0] = (short)f2bf(f0.x); t[1] = (short)f2bf(f0.y);
      t[2] = (short)f2bf(f0.z); t[3] = (short)f2bf(f0.w);
      t[4] = (short)f2bf(f1.x); t[5] = (short)f2bf(f1.y);
      t[6] = (short)f2bf(f1.z); t[7] = (short)f2bf(f1.w);
      rB[kt] = t;
    }
    const float* wrow = Wg + (size_t)(jbase + n16) * I_;
#pragma unroll
    for (int kt = 0; kt < 8; ++kt) {
      int k0 = kt * 32 + kg * 8;
      float4 f0 = *(const float4*)(wrow + k0);
      float4 f1 = *(const float4*)(wrow + k0 + 4);
      bf16x8 t;
      t[0] = (short)f2bf(f0.x); t[1] = (short)f2bf(f0.y);
      t[2] = (short)f2bf(f0.z); t[3] = (short)f2bf(f0.w);
      t[4] = (short)f2bf(f1.x); t[5] = (short)f2bf(f1.y);
      t[6] = (short)f2bf(f1.z); t[7] = (short)f2bf(f1.w);
      wB[kt] = t;
    }
  }
  const float bias = bg[jbase + n16];

  const int cb = tid >> 4;  // combine: batch row 0..15
  const int cn = tid & 15;  // combine: col within slice

  float c_state = 0.f;
  float h_sum = 0.f;
  bool dead = false;
  unsigned* flg = flags + cluster * 64;  // 32 used; 256B stride isolates lines

  __syncthreads();  // x_lds0/1 staged

  // accW(0) = bias + x(0)@W^T
  f32x4 accW = {bias, bias, bias, bias};
#pragma unroll
  for (int kt = 0; kt < 8; ++kt) {
    int k0 = kt * 32 + kg * 8;
    bf16x8 a = *(const bf16x8*)(&x_lds0[(n16 * 512 + k0 * 2) ^ ((n16 & 7) << 4)]);
    accW = __builtin_amdgcn_mfma_f32_16x16x32_bf16(a, wB[kt], accW, 0, 0, 0);
  }

  for (int t = 0; t < T_; ++t) {
    const unsigned long long* hin64 =
        (const unsigned long long*)(hbuf32 + (size_t)(t & 1) * (B_ * H_ / 2));
    unsigned* hout32 = hbuf32 + (size_t)((t + 1) & 1) * (B_ * H_ / 2);

    // ---- stage h(t-1): 16 rows x 128 qwords via b64 agent loads -> LDS.
    // Also issue x(t+2) loads (consumed in the wait section).
    float4 xv[4];
    const bool havex = (t + 2) < T_;
    if (havex) {
#pragma unroll
      for (int i = 0; i < 4; ++i) {
        int ci = i * 256 + tid;
        int row = ci >> 6, cf = (ci & 63) * 4;
        xv[i] = *(const float4*)(x + ((size_t)(rowbase + row) * T_ + (t + 2)) * I_ + cf);
      }
    }
#pragma unroll
    for (int i = 0; i < 8; ++i) {
      int id = i * 256 + tid;          // 0..2047: 16 rows x 128 qwords
      int row = id >> 7, w8 = id & 127;
      unsigned long long v =
          __hip_atomic_load(&hin64[(size_t)(rowbase + row) * 128 + w8],
                            __ATOMIC_RELAXED, __HIP_MEMORY_SCOPE_AGENT);
      *(unsigned long long*)(&h_lds[(row * 1024 + w8 * 8) ^ ((row & 7) << 4)]) = v;
    }
    __syncthreads();  // [A] h_lds ready

    // ---- R MFMAs only on the critical path (x part precomputed in accW)
    f32x4 acc = accW;
#pragma unroll
    for (int kt = 0; kt < 16; ++kt) {
      int k0 = kt * 32 + kg * 8;
      bf16x8 a = *(const bf16x8*)(&h_lds[(n16 * 1024 + k0 * 2) ^ ((n16 & 7) << 4)]);
      acc = __builtin_amdgcn_mfma_f32_16x16x32_bf16(a, rB[kt], acc, 0, 0, 0);
    }
    // C/D layout: col = lane&15, row = (lane>>4)*4 + r
#pragma unroll
    for (int r = 0; r < 4; ++r) {
      float p = acc[r];
      gates[g][kg * 4 + r][n16] = (g == 0) ? tanh_f(p) : sigm_f(p);
    }
    __syncthreads();  // [B]

    // ---- combine + publish h(t) (packed 2xbf16, relaxed agent store -> IC)
    float zv = gates[0][cb][cn], sv = gates[1][cb][cn];
    float fv = gates[2][cb][cn], ov = gates[3][cb][cn];
    c_state = sv * zv + fv * c_state;
    float hv = ov * tanh_f(c_state);
    h_sum += hv;
    {
      unsigned hb = (unsigned)f2bf(hv);
      unsigned nb = __shfl_down(hb, 1, 64);  // col cn+1, same row
      if ((lane & 1) == 0) {
        unsigned packed = hb | (nb << 16);
        __hip_atomic_store(&hout32[((size_t)(rowbase + cb) << 8) + ((jbase + cn) >> 1)],
                           packed, __ATOMIC_RELAXED, __HIP_MEMORY_SCOPE_AGENT);
      }
    }

    if (t + 1 < T_) {
      __syncthreads();  // [C] vmcnt(0) drain: h stores at the coherence point
      if (tid == 0) {
        __hip_atomic_store(&flg[w], (unsigned)(t + 1),
                           __ATOMIC_RELAXED, __HIP_MEMORY_SCOPE_AGENT);
      }
      // ---- off-critical-path work during the barrier wait:
      // accW(t+1) = bias + x(t+1)@W^T from the other x buffer; then stage
      // x(t+2) into the buffer just consumed.
      {
        f32x4 aw = {bias, bias, bias, bias};
        const char* xb = ((t + 1) & 1) ? x_lds1 : x_lds0;
#pragma unroll
        for (int kt = 0; kt < 8; ++kt) {
          int k0 = kt * 32 + kg * 8;
          bf16x8 a = *(const bf16x8*)(&xb[(n16 * 512 + k0 * 2) ^ ((n16 & 7) << 4)]);
          aw = __builtin_amdgcn_mfma_f32_16x16x32_bf16(a, wB[kt], aw, 0, 0, 0);
        }
        accW = aw;
      }
      if (havex) {
        char* xw = (t & 1) ? x_lds1 : x_lds0;
#pragma unroll
        for (int i = 0; i < 4; ++i) {
          int ci = i * 256 + tid;
          int row = ci >> 6, cf = (ci & 63) * 4;
          ushort4 pk;
          pk.x = f2bf(xv[i].x); pk.y = f2bf(xv[i].y);
          pk.z = f2bf(xv[i].z); pk.w = f2bf(xv[i].w);
          *(ushort4*)(&xw[(row * 512 + cf * 2) ^ ((row & 7) << 4)]) = pk;
        }
      }
      // ---- throttled poll: wave 0 only; lane i watches WG (i&31)'s flag.
      // First check immediate (fast path), then s_sleep(8) (~0.2us) between
      // checks to keep the IC free for flag stores and h loads. Bounded spin
      // (sticky dead) as anti-hang insurance; a real wait is <10us.
      if (tid < 64 && !dead) {
        const unsigned tgt = (unsigned)(t + 1);
        unsigned v = __hip_atomic_load(&flg[lane & 31],
                                       __ATOMIC_RELAXED, __HIP_MEMORY_SCOPE_AGENT);
        if (!__all((int)(v >= tgt))) {
          int guard = 0;
          for (;;) {
            __builtin_amdgcn_s_sleep(8);
            v = __hip_atomic_load(&flg[lane & 31],
                                  __ATOMIC_RELAXED, __HIP_MEMORY_SCOPE_AGENT);
            if (__all((int)(v >= tgt))) break;
            if (++guard > (1 << 20)) { dead = true; break; }
          }
        }
      }
      __syncthreads();  // [D] all h(t) visible; safe to stage next h
    }
  }

  // ---- epilogue: mean over T
  out[(size_t)(rowbase + cb) * H_ + (jbase + cn)] = h_sum * (1.0f / (float)T_);
}

extern "C" void kernel_launch(void* const* d_in, const int* in_sizes, int n_in,
                              void* d_out, int out_size, void* d_ws, size_t ws_size,
                              hipStream_t stream) {
  const float* x  = (const float*)d_in[0];
  const float* Wz = (const float*)d_in[1];
  const float* Ws = (const float*)d_in[2];
  const float* Wf = (const float*)d_in[3];
  const float* Wo = (const float*)d_in[4];
  const float* Rz = (const float*)d_in[5];
  const float* Rs = (const float*)d_in[6];
  const float* Rf = (const float*)d_in[7];
  const float* Ro = (const float*)d_in[8];
  const float* bz = (const float*)d_in[9];
  const float* bs = (const float*)d_in[10];
  const float* bf_ = (const float*)d_in[11];
  const float* bo = (const float*)d_in[12];

  // ws: [0, 256KiB) h double-buffer (2xbf16 per u32), then 8x64 u32 flags
  unsigned* hbuf32 = (unsigned*)d_ws;
  unsigned* flags = (unsigned*)((char*)d_ws + 262144);

  hipMemsetAsync(d_ws, 0, 262144 + 2048, stream);

  lstm_persistent<<<256, 256, 0, stream>>>(x, Wz, Ws, Wf, Wo, Rz, Rs, Rf, Ro,
                                           bz, bs, bf_, bo,
                                           (float*)d_out, hbuf32, flags);
}

// Round 11
// 1438.301 us; speedup vs baseline: 3.4036x; 1.5279x over previous
//
#include <hip/hip_runtime.h>

// LSTM encoder, persistent-kernel formulation (round 10 kernel, resubmitted
// after GPU-acquisition timeout — byte-identical; not yet measured).
// B=128, T=512, I=256, H=512.
// 8 clusters x 32 WGs; cluster c owns batch rows [16c,16c+16); WG w owns
// h-cols [16w,16w+16). Waves 0..3 = gates z,s,f,o; R/W fragments in registers.
//
// Protocol: round-9 (PROVEN: 2197us, absmax 0.0039) with ONE change:
//   h bulk staging uses PLAIN uint4 (b128) loads after a per-step
//   `buffer_inv sc0` (L1-only invalidate), instead of agent-scope atomic b64
//   loads. Evidence: FETCH_SIZE shows agent loads are L2-served (2.1GB of
//   redundant reads never hit EA), so the exchange already flows through the
//   XCD L2 -- the remaining cost is attributed to the L2 ATOMIC slow path
//   (serialized), which plain loads avoid. Flag barrier + h publish stores
//   remain agent-scope (proven propagation; only ~160 atomic ops/WG/step).

#define B_ 128
#define T_ 512
#define I_ 256
#define H_ 512

typedef __attribute__((ext_vector_type(8))) short bf16x8;
typedef __attribute__((ext_vector_type(4))) float f32x4;

__device__ __forceinline__ unsigned short f2bf(float f) {
  union { float f; unsigned u; } v; v.f = f;
  unsigned r = v.u + 0x7FFFu + ((v.u >> 16) & 1u);  // RNE; inputs finite
  return (unsigned short)(r >> 16);
}

__device__ __forceinline__ float sigm_f(float x) { return 1.f / (1.f + __expf(-x)); }
__device__ __forceinline__ float tanh_f(float x) { return 1.f - 2.f / (__expf(2.f * x) + 1.f); }

__global__ __launch_bounds__(256, 1)
void lstm_persistent(const float* __restrict__ x,
                     const float* __restrict__ Wz, const float* __restrict__ Ws,
                     const float* __restrict__ Wf, const float* __restrict__ Wo,
                     const float* __restrict__ Rz, const float* __restrict__ Rs,
                     const float* __restrict__ Rf, const float* __restrict__ Ro,
                     const float* __restrict__ bz, const float* __restrict__ bs,
                     const float* __restrict__ bf_, const float* __restrict__ bo,
                     float* __restrict__ out,
                     unsigned* __restrict__ hbuf32,   // [2][128][256] u32 (2xbf16)
                     unsigned* __restrict__ flags) {  // [8][64] u32, monotonic
  const int tid = threadIdx.x;
  const int bid = blockIdx.x;
  const int cluster = bid & 7;
  const int w = bid >> 3;
  const int rowbase = cluster * 16;
  const int jbase = w * 16;
  const int g = tid >> 6;            // wave id == gate (0=z,1=s,2=f,3=o)
  const int lane = tid & 63;
  const int n16 = lane & 15;
  const int kg = lane >> 4;

  __shared__ __align__(16) char h_lds[16 * 1024];   // [16 rows][512 bf16], XOR-swizzled
  __shared__ __align__(16) char x_lds0[16 * 512];   // [16 rows][256 bf16], XOR-swizzled
  __shared__ __align__(16) char x_lds1[16 * 512];
  __shared__ float gates[4][16][16];

  const float* Wg = (g == 0) ? Wz : (g == 1) ? Ws : (g == 2) ? Wf : Wo;
  const float* Rg = (g == 0) ? Rz : (g == 1) ? Rs : (g == 2) ? Rf : Ro;
  const float* bg = (g == 0) ? bz : (g == 1) ? bs : (g == 2) ? bf_ : bo;

  // ---- stage x(0)->x_lds0, x(1)->x_lds1
#pragma unroll
  for (int i = 0; i < 4; ++i) {
    int ci = i * 256 + tid;
    int row = ci >> 6, cf = (ci & 63) * 4;
    const float4 v0 = *(const float4*)(x + ((size_t)(rowbase + row) * T_ + 0) * I_ + cf);
    const float4 v1 = *(const float4*)(x + ((size_t)(rowbase + row) * T_ + 1) * I_ + cf);
    ushort4 p0, p1;
    p0.x = f2bf(v0.x); p0.y = f2bf(v0.y); p0.z = f2bf(v0.z); p0.w = f2bf(v0.w);
    p1.x = f2bf(v1.x); p1.y = f2bf(v1.y); p1.z = f2bf(v1.z); p1.w = f2bf(v1.w);
    *(ushort4*)(&x_lds0[(row * 512 + cf * 2) ^ ((row & 7) << 4)]) = p0;
    *(ushort4*)(&x_lds1[(row * 512 + cf * 2) ^ ((row & 7) << 4)]) = p1;
  }

  // ---- R (16 k-tiles) and W (8 k-tiles) B-fragments resident in registers.
  bf16x8 rB[16];
  bf16x8 wB[8];
  {
    const float* rrow = Rg + (size_t)(jbase + n16) * H_;
#pragma unroll
    for (int kt = 0; kt < 16; ++kt) {
      int k0 = kt * 32 + kg * 8;
      float4 f0 = *(const float4*)(rrow + k0);
      float4 f1 = *(const float4*)(rrow + k0 + 4);
      bf16x8 t;
      t[0] = (short)f2bf(f0.x); t[1] = (short)f2bf(f0.y);
      t[2] = (short)f2bf(f0.z); t[3] = (short)f2bf(f0.w);
      t[4] = (short)f2bf(f1.x); t[5] = (short)f2bf(f1.y);
      t[6] = (short)f2bf(f1.z); t[7] = (short)f2bf(f1.w);
      rB[kt] = t;
    }
    const float* wrow = Wg + (size_t)(jbase + n16) * I_;
#pragma unroll
    for (int kt = 0; kt < 8; ++kt) {
      int k0 = kt * 32 + kg * 8;
      float4 f0 = *(const float4*)(wrow + k0);
      float4 f1 = *(const float4*)(wrow + k0 + 4);
      bf16x8 t;
      t[0] = (short)f2bf(f0.x); t[1] = (short)f2bf(f0.y);
      t[2] = (short)f2bf(f0.z); t[3] = (short)f2bf(f0.w);
      t[4] = (short)f2bf(f1.x); t[5] = (short)f2bf(f1.y);
      t[6] = (short)f2bf(f1.z); t[7] = (short)f2bf(f1.w);
      wB[kt] = t;
    }
  }
  const float bias = bg[jbase + n16];

  const int cb = tid >> 4;  // combine: batch row 0..15
  const int cn = tid & 15;  // combine: col within slice

  float c_state = 0.f;
  float h_sum = 0.f;
  bool dead = false;
  unsigned* flg = flags + cluster * 64;  // 32 used; 256B stride isolates lines

  __syncthreads();  // x_lds0/1 staged

  // accW(0) = bias + x(0)@W^T
  f32x4 accW = {bias, bias, bias, bias};
#pragma unroll
  for (int kt = 0; kt < 8; ++kt) {
    int k0 = kt * 32 + kg * 8;
    bf16x8 a = *(const bf16x8*)(&x_lds0[(n16 * 512 + k0 * 2) ^ ((n16 & 7) << 4)]);
    accW = __builtin_amdgcn_mfma_f32_16x16x32_bf16(a, wB[kt], accW, 0, 0, 0);
  }

  for (int t = 0; t < T_; ++t) {
    const char* hin = (const char*)(hbuf32 + (size_t)(t & 1) * (B_ * H_ / 2));
    unsigned* hout32 = hbuf32 + (size_t)((t + 1) & 1) * (B_ * H_ / 2);

    // ---- stage h(t-1): PLAIN b128 loads, L2 fast path. L1 may hold stale
    // lines from step t-2 (same parity buffer) -> one L1-only invalidate;
    // per-wave VMEM program order makes inv -> loads safe (same sequence the
    // compiler emits for acquire). Also issue x(t+2) loads (consumed late).
    asm volatile("buffer_inv sc0" ::: "memory");
    float4 xv[4];
    const bool havex = (t + 2) < T_;
    if (havex) {
#pragma unroll
      for (int i = 0; i < 4; ++i) {
        int ci = i * 256 + tid;
        int row = ci >> 6, cf = (ci & 63) * 4;
        xv[i] = *(const float4*)(x + ((size_t)(rowbase + row) * T_ + (t + 2)) * I_ + cf);
      }
    }
#pragma unroll
    for (int i = 0; i < 4; ++i) {
      int id = i * 256 + tid;          // 0..1023: 16 rows x 64 x 16B
      int row = id >> 6, o16 = (id & 63) * 16;
      uint4 v = *(const uint4*)(hin + (size_t)(rowbase + row) * 1024 + o16);
      *(uint4*)(&h_lds[(row * 1024 + o16) ^ ((row & 7) << 4)]) = v;
    }
    __syncthreads();  // [A] h_lds ready

    // ---- R MFMAs only on the critical path (x part precomputed in accW)
    f32x4 acc = accW;
#pragma unroll
    for (int kt = 0; kt < 16; ++kt) {
      int k0 = kt * 32 + kg * 8;
      bf16x8 a = *(const bf16x8*)(&h_lds[(n16 * 1024 + k0 * 2) ^ ((n16 & 7) << 4)]);
      acc = __builtin_amdgcn_mfma_f32_16x16x32_bf16(a, rB[kt], acc, 0, 0, 0);
    }
    // C/D layout: col = lane&15, row = (lane>>4)*4 + r
#pragma unroll
    for (int r = 0; r < 4; ++r) {
      float p = acc[r];
      gates[g][kg * 4 + r][n16] = (g == 0) ? tanh_f(p) : sigm_f(p);
    }
    __syncthreads();  // [B]

    // ---- combine + publish h(t) (packed 2xbf16, relaxed agent store)
    float zv = gates[0][cb][cn], sv = gates[1][cb][cn];
    float fv = gates[2][cb][cn], ov = gates[3][cb][cn];
    c_state = sv * zv + fv * c_state;
    float hv = ov * tanh_f(c_state);
    h_sum += hv;
    {
      unsigned hb = (unsigned)f2bf(hv);
      unsigned nb = __shfl_down(hb, 1, 64);  // col cn+1, same row
      if ((lane & 1) == 0) {
        unsigned packed = hb | (nb << 16);
        __hip_atomic_store(&hout32[((size_t)(rowbase + cb) << 8) + ((jbase + cn) >> 1)],
                           packed, __ATOMIC_RELAXED, __HIP_MEMORY_SCOPE_AGENT);
      }
    }

    if (t + 1 < T_) {
      __syncthreads();  // [C] vmcnt(0) drain: h stores at the coherence point
      if (tid == 0) {
        __hip_atomic_store(&flg[w], (unsigned)(t + 1),
                           __ATOMIC_RELAXED, __HIP_MEMORY_SCOPE_AGENT);
      }
      // ---- off-critical-path work during the barrier wait:
      // accW(t+1) = bias + x(t+1)@W^T from the other x buffer; then stage
      // x(t+2) into the buffer just consumed.
      {
        f32x4 aw = {bias, bias, bias, bias};
        const char* xb = ((t + 1) & 1) ? x_lds1 : x_lds0;
#pragma unroll
        for (int kt = 0; kt < 8; ++kt) {
          int k0 = kt * 32 + kg * 8;
          bf16x8 a = *(const bf16x8*)(&xb[(n16 * 512 + k0 * 2) ^ ((n16 & 7) << 4)]);
          aw = __builtin_amdgcn_mfma_f32_16x16x32_bf16(a, wB[kt], aw, 0, 0, 0);
        }
        accW = aw;
      }
      if (havex) {
        char* xw = (t & 1) ? x_lds1 : x_lds0;
#pragma unroll
        for (int i = 0; i < 4; ++i) {
          int ci = i * 256 + tid;
          int row = ci >> 6, cf = (ci & 63) * 4;
          ushort4 pk;
          pk.x = f2bf(xv[i].x); pk.y = f2bf(xv[i].y);
          pk.z = f2bf(xv[i].z); pk.w = f2bf(xv[i].w);
          *(ushort4*)(&xw[(row * 512 + cf * 2) ^ ((row & 7) << 4)]) = pk;
        }
      }
      // ---- throttled poll: wave 0 only; lane i watches WG (i&31)'s flag.
      // First check immediate, then s_sleep(8) (~0.2us) between checks.
      // Bounded spin (sticky dead) as anti-hang insurance.
      if (tid < 64 && !dead) {
        const unsigned tgt = (unsigned)(t + 1);
        unsigned v = __hip_atomic_load(&flg[lane & 31],
                                       __ATOMIC_RELAXED, __HIP_MEMORY_SCOPE_AGENT);
        if (!__all((int)(v >= tgt))) {
          int guard = 0;
          for (;;) {
            __builtin_amdgcn_s_sleep(8);
            v = __hip_atomic_load(&flg[lane & 31],
                                  __ATOMIC_RELAXED, __HIP_MEMORY_SCOPE_AGENT);
            if (__all((int)(v >= tgt))) break;
            if (++guard > (1 << 20)) { dead = true; break; }
          }
        }
      }
      __syncthreads();  // [D] all h(t) visible; safe to stage next h
    }
  }

  // ---- epilogue: mean over T
  out[(size_t)(rowbase + cb) * H_ + (jbase + cn)] = h_sum * (1.0f / (float)T_);
}

extern "C" void kernel_launch(void* const* d_in, const int* in_sizes, int n_in,
                              void* d_out, int out_size, void* d_ws, size_t ws_size,
                              hipStream_t stream) {
  const float* x  = (const float*)d_in[0];
  const float* Wz = (const float*)d_in[1];
  const float* Ws = (const float*)d_in[2];
  const float* Wf = (const float*)d_in[3];
  const float* Wo = (const float*)d_in[4];
  const float* Rz = (const float*)d_in[5];
  const float* Rs = (const float*)d_in[6];
  const float* Rf = (const float*)d_in[7];
  const float* Ro = (const float*)d_in[8];
  const float* bz = (const float*)d_in[9];
  const float* bs = (const float*)d_in[10];
  const float* bf_ = (const float*)d_in[11];
  const float* bo = (const float*)d_in[12];

  // ws: [0, 256KiB) h double-buffer (2xbf16 per u32), then 8x64 u32 flags
  unsigned* hbuf32 = (unsigned*)d_ws;
  unsigned* flags = (unsigned*)((char*)d_ws + 262144);

  hipMemsetAsync(d_ws, 0, 262144 + 2048, stream);

  lstm_persistent<<<256, 256, 0, stream>>>(x, Wz, Ws, Wf, Wo, Rz, Rs, Rf, Ro,
                                           bz, bs, bf_, bo,
                                           (float*)d_out, hbuf32, flags);
}